// Round 4
// baseline (604.499 us; speedup 1.0000x reference)
//
#include <hip/hip_runtime.h>

typedef __attribute__((ext_vector_type(8))) short short8;
typedef __attribute__((ext_vector_type(4))) float float4_t;
typedef unsigned short u16;

#define K_DIM 768

__device__ __forceinline__ u16 f2bf(float f) {
  union { float f; unsigned u; } v; v.f = f;
  unsigned r = v.u + 0x7FFFu + ((v.u >> 16) & 1u);
  return (u16)(r >> 16);
}

__device__ __forceinline__ u16 f2bf_trunc(float f) {
  union { float f; unsigned u; } v; v.f = f;
  return (u16)(v.u >> 16);
}

__device__ __forceinline__ void gload16(const void* g, void* l) {
  __builtin_amdgcn_global_load_lds(
      (__attribute__((address_space(1))) void*)g,
      (__attribute__((address_space(3))) void*)l, 16, 0, 0);
}

// ---------------- fp32 -> bf16 convert (vectorized) ----------------
__global__ __launch_bounds__(256) void cvt_kernel(const float* __restrict__ src,
                                                  u16* __restrict__ dst, int n4) {
  int i = blockIdx.x * 256 + threadIdx.x;
  if (i >= n4) return;
  float4 v = ((const float4*)src)[i];
  union { u16 h[4]; unsigned long long ll; } o;
  o.h[0] = f2bf(v.x); o.h[1] = f2bf(v.y); o.h[2] = f2bf(v.z); o.h[3] = f2bf(v.w);
  ((unsigned long long*)dst)[i] = o.ll;
}

// bank_k (256,768) -> bk[h][m][d] bf16 ; bank_v -> bvt[h][d][m] bf16 (transposed)
__global__ __launch_bounds__(256) void cvt_bank_kernel(const float* __restrict__ bkf,
                                                       const float* __restrict__ bvf,
                                                       u16* __restrict__ bk,
                                                       u16* __restrict__ bvt) {
  int idx = blockIdx.x * 256 + threadIdx.x;  // < 196608
  int m = idx / 768;
  int c = idx - m * 768;
  int h = c >> 6, d = c & 63;
  bk[(h * 256 + m) * 64 + d] = f2bf(bkf[idx]);
  bvt[(h * 64 + d) * 256 + m] = f2bf(bvf[idx]);
}

// ---------------- 128x128x32 bf16 GEMM, C = A * B^T  ----------------
template <int MODE>
__global__ __launch_bounds__(256) void gemm128(
    const u16* __restrict__ A, const u16* __restrict__ Bw,
    const float* __restrict__ bias,
    u16* __restrict__ q_ws, u16* __restrict__ k_ws, u16* __restrict__ vt_ws,
    float* __restrict__ p_out) {
  __shared__ u16 As[128 * 32];
  __shared__ u16 Bs[128 * 32];
  const int tid = threadIdx.x;
  const int w = tid >> 6, lane = tid & 63;
  const int l15 = lane & 15, quad = lane >> 4;
  const int wm = w >> 1, wn = w & 1;
  const int bm = blockIdx.y, bn = blockIdx.x;

  float4_t acc[4][4];
#pragma unroll
  for (int i = 0; i < 4; i++)
#pragma unroll
    for (int j = 0; j < 4; j++) acc[i][j] = (float4_t){0.f, 0.f, 0.f, 0.f};

  for (int kt = 0; kt < K_DIM; kt += 32) {
    __syncthreads();
#pragma unroll
    for (int r = 0; r < 2; r++) {
      const int off = (w * 2 + r) * 1024 + lane * 16;  // byte offset in 8KB tile
      const int row = off >> 6;                        // 64B per row (32 bf16)
      const int grp = (off & 63) >> 4;                 // phys 16B group 0..3
      const int lcol = (grp ^ (row & 3)) * 8;          // XOR-swizzled logical col
      gload16(A + (size_t)(bm * 128 + row) * K_DIM + kt + lcol, (char*)As + off);
      gload16(Bw + (size_t)(bn * 128 + row) * K_DIM + kt + lcol, (char*)Bs + off);
    }
    __syncthreads();
    short8 af[4], bfr[4];
#pragma unroll
    for (int mt = 0; mt < 4; mt++) {
      const int row = wm * 64 + mt * 16 + l15;
      af[mt] = *(const short8*)(As + row * 32 + (quad ^ (row & 3)) * 8);
    }
#pragma unroll
    for (int nt = 0; nt < 4; nt++) {
      const int row = wn * 64 + nt * 16 + l15;
      bfr[nt] = *(const short8*)(Bs + row * 32 + (quad ^ (row & 3)) * 8);
    }
#pragma unroll
    for (int mt = 0; mt < 4; mt++)
#pragma unroll
      for (int nt = 0; nt < 4; nt++)
        acc[mt][nt] = __builtin_amdgcn_mfma_f32_16x16x32_bf16(af[mt], bfr[nt], acc[mt][nt], 0, 0, 0);
  }

  const float QS = 0.18033688011112042f;  // (1/8) * log2(e)
#pragma unroll
  for (int mt = 0; mt < 4; mt++) {
#pragma unroll
    for (int nt = 0; nt < 4; nt++) {
      const int row0 = bm * 128 + wm * 64 + mt * 16 + quad * 4;
      const int f = bn * 128 + wn * 64 + nt * 16 + l15;
      const float bv = bias[f];
      if (MODE == 0) {
        const int which = f / 768;
        const int rem = f - which * 768;
        const int h = rem >> 6, d = rem & 63;
#pragma unroll
        for (int r2 = 0; r2 < 4; r2++) {
          float v = acc[mt][nt][r2] + bv;
          const int i = row0 + r2;
          const int bb = i >> 10, n = i & 1023;
          const size_t bhh = (size_t)(bb * 12 + h);
          if (which == 0)      q_ws[(bhh * 1024 + n) * 64 + d] = f2bf(v * QS);
          else if (which == 1) k_ws[(bhh * 1024 + n) * 64 + d] = f2bf(v);
          else                 vt_ws[(bhh * 64 + d) * 1024 + n] = f2bf(v);
        }
      } else {
#pragma unroll
        for (int r2 = 0; r2 < 4; r2++) {
          const int i = row0 + r2;
          p_out[(size_t)i * 768 + f] = acc[mt][nt][r2] + bv;
        }
      }
    }
  }
}

// ---------------- flash attention, barrier-free -----------------------------
// grid (192 bh, 8 qblocks): all 8 q-blocks of one bh have ids ≡ bh (mod 192),
// 192 % 8 == 0 -> same XCD -> K/V served from that XCD's L2.
// K/V MFMA fragments load DIRECTLY from global (16B contiguous chunks in the
// k_ws[m][d] / vt_ws[d][m] layouts) -> no LDS staging, no __syncthreads in
// the K-loop. LDS holds only the per-wave P transpose buffer.
__global__ __launch_bounds__(256, 4) void fa_kernel(
    const u16* __restrict__ qws, const u16* __restrict__ kws,
    const u16* __restrict__ vtws, const u16* __restrict__ bk,
    const u16* __restrict__ bvt,
    float* __restrict__ out, u16* __restrict__ obf) {
  __shared__ u16 Ps[4][32 * 64];     // per-wave P tile [q][m], XOR-swizzled

  const int tid = threadIdx.x;
  const int w = tid >> 6, lane = tid & 63;
  const int l15 = lane & 15, quad = lane >> 4;
  const int bh = blockIdx.x;
  const int b = bh / 12, h = bh - b * 12;
  const int q0 = blockIdx.y * 128 + w * 32;

  short8 qf[2][2];
  {
    const u16* qb = qws + ((size_t)bh * 1024 + q0) * 64;
#pragma unroll
    for (int rt = 0; rt < 2; rt++)
#pragma unroll
      for (int c = 0; c < 2; c++)
        qf[rt][c] = *(const short8*)(qb + (rt * 16 + l15) * 64 + c * 32 + quad * 8);
  }

  const short ONE = (short)0x3F80;  // bf16 1.0
  const short8 onesf = (short8){ONE, ONE, ONE, ONE, ONE, ONE, ONE, ONE};

  float4_t O[2][4];
  float4_t lacc[2];
#pragma unroll
  for (int rt = 0; rt < 2; rt++) {
#pragma unroll
    for (int dt = 0; dt < 4; dt++) O[rt][dt] = (float4_t){0.f, 0.f, 0.f, 0.f};
    lacc[rt] = (float4_t){0.f, 0.f, 0.f, 0.f};
  }

  for (int t = 0; t < 20; t++) {
    const int mb = t * 64;
    const u16* kb;
    const u16* vb;
    int vs;
    if (mb < 1024) {
      kb = kws + ((size_t)bh * 1024 + mb) * 64;
      vb = vtws + (size_t)bh * 65536 + mb;
      vs = 1024;
    } else {
      kb = bk + ((size_t)h * 256 + (mb - 1024)) * 64;
      vb = bvt + (size_t)h * 16384 + (mb - 1024);
      vs = 256;
    }

    // K fragments straight from global: B-op lane map = [m=ct*16+l15][d: c*32+quad*8 ..+8]
    short8 kf[4][2];
#pragma unroll
    for (int ct = 0; ct < 4; ct++)
#pragma unroll
      for (int c = 0; c < 2; c++)
        kf[ct][c] = *(const short8*)(kb + (ct * 16 + l15) * 64 + c * 32 + quad * 8);

    float4_t S[2][4];
#pragma unroll
    for (int rt = 0; rt < 2; rt++)
#pragma unroll
      for (int ct = 0; ct < 4; ct++) {
        float4_t z = (float4_t){0.f, 0.f, 0.f, 0.f};
        z = __builtin_amdgcn_mfma_f32_16x16x32_bf16(qf[rt][0], kf[ct][0], z, 0, 0, 0);
        S[rt][ct] = __builtin_amdgcn_mfma_f32_16x16x32_bf16(qf[rt][1], kf[ct][1], z, 0, 0, 0);
      }

    // exp2 (scores bounded, no overflow) + truncating bf16 pack -> LDS
#pragma unroll
    for (int rt = 0; rt < 2; rt++) {
#pragma unroll
      for (int ct = 0; ct < 4; ct++) {
        const int colg = ct * 2 + (l15 >> 3);
#pragma unroll
        for (int r = 0; r < 4; r++) {
          const float p = __builtin_amdgcn_exp2f(S[rt][ct][r]);
          const int q = rt * 16 + quad * 4 + r;
          Ps[w][q * 64 + (colg ^ (q & 7)) * 8 + (l15 & 7)] = f2bf_trunc(p);
        }
      }
    }

    // V fragments straight from global: [d=dt*16+l15][m: c*32+quad*8 ..+8]
    short8 vf[4][2];
#pragma unroll
    for (int dt = 0; dt < 4; dt++)
#pragma unroll
      for (int c = 0; c < 2; c++)
        vf[dt][c] = *(const short8*)(vb + (dt * 16 + l15) * vs + c * 32 + quad * 8);

#pragma unroll
    for (int rt = 0; rt < 2; rt++)
#pragma unroll
      for (int c = 0; c < 2; c++) {
        const int qrow = rt * 16 + l15;
        const short8 pf = *(const short8*)(&Ps[w][qrow * 64 + (((c * 4 + quad) ^ (qrow & 7)) * 8)]);
#pragma unroll
        for (int dt = 0; dt < 4; dt++)
          O[rt][dt] = __builtin_amdgcn_mfma_f32_16x16x32_bf16(pf, vf[dt][c], O[rt][dt], 0, 0, 0);
        lacc[rt] = __builtin_amdgcn_mfma_f32_16x16x32_bf16(pf, onesf, lacc[rt], 0, 0, 0);
      }
  }

#pragma unroll
  for (int rt = 0; rt < 2; rt++) {
    float rl[4];
#pragma unroll
    for (int r = 0; r < 4; r++) rl[r] = 1.f / lacc[rt][r];
#pragma unroll
    for (int dt = 0; dt < 4; dt++)
#pragma unroll
      for (int r = 0; r < 4; r++) {
        const float v = O[rt][dt][r] * rl[r];
        const int n = q0 + rt * 16 + quad * 4 + r;
        const int d = dt * 16 + l15;
        const size_t idx = ((size_t)b * 1024 + n) * 768 + h * 64 + d;
        out[idx] = v;
        obf[idx] = f2bf(v);
      }
  }
}

// ---------------- in-place LayerNorm over 768 ----------------
__global__ __launch_bounds__(256) void ln_kernel(float* __restrict__ p,
                                                 const float* __restrict__ nw,
                                                 const float* __restrict__ nb) {
  __shared__ float red[2][4];
  const int row = blockIdx.x, tid = threadIdx.x;
  float* pr = p + (size_t)row * 768;
  const float x0 = pr[tid], x1 = pr[tid + 256], x2 = pr[tid + 512];
  float s = x0 + x1 + x2;
  float sq = x0 * x0 + x1 * x1 + x2 * x2;
#pragma unroll
  for (int m = 1; m < 64; m <<= 1) {
    s += __shfl_xor(s, m, 64);
    sq += __shfl_xor(sq, m, 64);
  }
  const int w = tid >> 6;
  if ((tid & 63) == 0) { red[0][w] = s; red[1][w] = sq; }
  __syncthreads();
  s = red[0][0] + red[0][1] + red[0][2] + red[0][3];
  sq = red[1][0] + red[1][1] + red[1][2] + red[1][3];
  const float mean = s * (1.0f / 768.0f);
  const float var = sq * (1.0f / 768.0f) - mean * mean;
  const float rstd = rsqrtf(var + 1e-5f);
  pr[tid]       = (x0 - mean) * rstd * nw[tid]       + nb[tid];
  pr[tid + 256] = (x1 - mean) * rstd * nw[tid + 256] + nb[tid + 256];
  pr[tid + 512] = (x2 - mean) * rstd * nw[tid + 512] + nb[tid + 512];
}

extern "C" void kernel_launch(void* const* d_in, const int* in_sizes, int n_in,
                              void* d_out, int out_size, void* d_ws, size_t ws_size,
                              hipStream_t stream) {
  (void)in_sizes; (void)n_in; (void)out_size; (void)ws_size;
  const float* x      = (const float*)d_in[0];
  const float* qkv_w  = (const float*)d_in[1];
  const float* qkv_b  = (const float*)d_in[2];
  const float* proj_w = (const float*)d_in[3];
  const float* proj_b = (const float*)d_in[4];
  const float* norm_w = (const float*)d_in[5];
  const float* norm_b = (const float*)d_in[6];
  const float* bank_k = (const float*)d_in[7];
  const float* bank_v = (const float*)d_in[8];

  char* ws = (char*)d_ws;
  u16* xbf   = (u16*)(ws + 0);           // 16384x768 bf16 = 25165824
  u16* obf   = (u16*)(ws + 0);           // aliases xbf (dead after gemm<0>)
  u16* qwbf  = (u16*)(ws + 25165824);    // 2304x768  = 3538944
  u16* pwbf  = (u16*)(ws + 28704768);    // 768x768   = 1179648
  u16* bkbf  = (u16*)(ws + 29884416);    // 12x256x64 = 393216
  u16* bvtbf = (u16*)(ws + 30277632);    // 12x64x256 = 393216
  u16* q_ws  = (u16*)(ws + 30670848);    // 192x1024x64 = 25165824
  u16* k_ws  = (u16*)(ws + 55836672);
  u16* vt_ws = (u16*)(ws + 81002496);    // ends 106168320

  float* out0  = (float*)d_out;
  float* p_out = out0 + 12582912;        // second output region doubles as p scratch

  cvt_kernel<<<12288, 256, 0, stream>>>(x, xbf, 3145728);
  cvt_kernel<<<1728, 256, 0, stream>>>(qkv_w, qwbf, 442368);
  cvt_kernel<<<576, 256, 0, stream>>>(proj_w, pwbf, 147456);
  cvt_bank_kernel<<<768, 256, 0, stream>>>(bank_k, bank_v, bkbf, bvtbf);

  gemm128<0><<<dim3(18, 128), 256, 0, stream>>>(xbf, qwbf, qkv_b, q_ws, k_ws, vt_ws, nullptr);
  fa_kernel<<<dim3(192, 8), 256, 0, stream>>>(q_ws, k_ws, vt_ws, bkbf, bvtbf, out0, obf);
  gemm128<1><<<dim3(6, 128), 256, 0, stream>>>(obf, pwbf, proj_b, nullptr, nullptr, nullptr, p_out);
  ln_kernel<<<16384, 256, 0, stream>>>(p_out, norm_w, norm_b);
}

// Round 5
// 440.426 us; speedup vs baseline: 1.3725x; 1.3725x over previous
//
#include <hip/hip_runtime.h>

typedef __attribute__((ext_vector_type(8))) short short8;
typedef __attribute__((ext_vector_type(4))) float float4_t;
typedef unsigned short u16;

#define K_DIM 768

__device__ __forceinline__ u16 f2bf(float f) {
  union { float f; unsigned u; } v; v.f = f;
  unsigned r = v.u + 0x7FFFu + ((v.u >> 16) & 1u);
  return (u16)(r >> 16);
}

__device__ __forceinline__ u16 f2bf_trunc(float f) {
  union { float f; unsigned u; } v; v.f = f;
  return (u16)(v.u >> 16);
}

__device__ __forceinline__ void gload16(const void* g, void* l) {
  __builtin_amdgcn_global_load_lds(
      (__attribute__((address_space(1))) void*)g,
      (__attribute__((address_space(3))) void*)l, 16, 0, 0);
}

// ---------------- fp32 -> bf16 convert (vectorized) ----------------
__global__ __launch_bounds__(256) void cvt_kernel(const float* __restrict__ src,
                                                  u16* __restrict__ dst, int n4) {
  int i = blockIdx.x * 256 + threadIdx.x;
  if (i >= n4) return;
  float4 v = ((const float4*)src)[i];
  union { u16 h[4]; unsigned long long ll; } o;
  o.h[0] = f2bf(v.x); o.h[1] = f2bf(v.y); o.h[2] = f2bf(v.z); o.h[3] = f2bf(v.w);
  ((unsigned long long*)dst)[i] = o.ll;
}

// bank_k (256,768) -> bk[h][m][d] bf16 ; bank_v -> bvt[h][d][m] bf16 (transposed)
__global__ __launch_bounds__(256) void cvt_bank_kernel(const float* __restrict__ bkf,
                                                       const float* __restrict__ bvf,
                                                       u16* __restrict__ bk,
                                                       u16* __restrict__ bvt) {
  int idx = blockIdx.x * 256 + threadIdx.x;  // < 196608
  int m = idx / 768;
  int c = idx - m * 768;
  int h = c >> 6, d = c & 63;
  bk[(h * 256 + m) * 64 + d] = f2bf(bkf[idx]);
  bvt[(h * 64 + d) * 256 + m] = f2bf(bvf[idx]);
}

// ---------------- 128x128x32 bf16 GEMM, C = A * B^T  ----------------
template <int MODE>
__global__ __launch_bounds__(256) void gemm128(
    const u16* __restrict__ A, const u16* __restrict__ Bw,
    const float* __restrict__ bias,
    u16* __restrict__ q_ws, u16* __restrict__ k_ws, u16* __restrict__ vt_ws,
    float* __restrict__ p_out) {
  __shared__ u16 As[128 * 32];
  __shared__ u16 Bs[128 * 32];
  const int tid = threadIdx.x;
  const int w = tid >> 6, lane = tid & 63;
  const int l15 = lane & 15, quad = lane >> 4;
  const int wm = w >> 1, wn = w & 1;
  const int bm = blockIdx.y, bn = blockIdx.x;

  float4_t acc[4][4];
#pragma unroll
  for (int i = 0; i < 4; i++)
#pragma unroll
    for (int j = 0; j < 4; j++) acc[i][j] = (float4_t){0.f, 0.f, 0.f, 0.f};

  for (int kt = 0; kt < K_DIM; kt += 32) {
    __syncthreads();
#pragma unroll
    for (int r = 0; r < 2; r++) {
      const int off = (w * 2 + r) * 1024 + lane * 16;  // byte offset in 8KB tile
      const int row = off >> 6;                        // 64B per row (32 bf16)
      const int grp = (off & 63) >> 4;                 // phys 16B group 0..3
      const int lcol = (grp ^ (row & 3)) * 8;          // XOR-swizzled logical col
      gload16(A + (size_t)(bm * 128 + row) * K_DIM + kt + lcol, (char*)As + off);
      gload16(Bw + (size_t)(bn * 128 + row) * K_DIM + kt + lcol, (char*)Bs + off);
    }
    __syncthreads();
    short8 af[4], bfr[4];
#pragma unroll
    for (int mt = 0; mt < 4; mt++) {
      const int row = wm * 64 + mt * 16 + l15;
      af[mt] = *(const short8*)(As + row * 32 + (quad ^ (row & 3)) * 8);
    }
#pragma unroll
    for (int nt = 0; nt < 4; nt++) {
      const int row = wn * 64 + nt * 16 + l15;
      bfr[nt] = *(const short8*)(Bs + row * 32 + (quad ^ (row & 3)) * 8);
    }
#pragma unroll
    for (int mt = 0; mt < 4; mt++)
#pragma unroll
      for (int nt = 0; nt < 4; nt++)
        acc[mt][nt] = __builtin_amdgcn_mfma_f32_16x16x32_bf16(af[mt], bfr[nt], acc[mt][nt], 0, 0, 0);
  }

  const float QS = 0.18033688011112042f;  // (1/8) * log2(e)
#pragma unroll
  for (int mt = 0; mt < 4; mt++) {
#pragma unroll
    for (int nt = 0; nt < 4; nt++) {
      const int row0 = bm * 128 + wm * 64 + mt * 16 + quad * 4;
      const int f = bn * 128 + wn * 64 + nt * 16 + l15;
      const float bv = bias[f];
      if (MODE == 0) {
        const int which = f / 768;
        const int rem = f - which * 768;
        const int h = rem >> 6, d = rem & 63;
#pragma unroll
        for (int r2 = 0; r2 < 4; r2++) {
          float v = acc[mt][nt][r2] + bv;
          const int i = row0 + r2;
          const int bb = i >> 10, n = i & 1023;
          const size_t bhh = (size_t)(bb * 12 + h);
          if (which == 0)      q_ws[(bhh * 1024 + n) * 64 + d] = f2bf(v * QS);
          else if (which == 1) k_ws[(bhh * 1024 + n) * 64 + d] = f2bf(v);
          else                 vt_ws[(bhh * 64 + d) * 1024 + n] = f2bf(v);
        }
      } else {
#pragma unroll
        for (int r2 = 0; r2 < 4; r2++) {
          const int i = row0 + r2;
          p_out[(size_t)i * 768 + f] = acc[mt][nt][r2] + bv;
        }
      }
    }
  }
}

// ---------------- flash attention (LDS-staged K/V, XCD-local grid) ---------
// grid (192 bh, 8 qblocks): the 8 q-blocks sharing one bh's K/V (256 KB) have
// block ids ≡ bh (mod 8·24) -> same XCD -> staging loads hit that XCD's L2.
// 4 waves x 32 Q-rows; K-tiles of 64 over M=1280.
// l-sum via extra MFMA against a ones B-fragment (P·1).
__global__ __launch_bounds__(256) void fa_kernel(
    const u16* __restrict__ qws, const u16* __restrict__ kws,
    const u16* __restrict__ vtws, const u16* __restrict__ bk,
    const u16* __restrict__ bvt,
    float* __restrict__ out, u16* __restrict__ obf) {
  __shared__ u16 Ks[64 * 64];        // [m][d], rows XOR-swizzled in 16B groups
  __shared__ u16 Vts[64 * 64];       // [d][m], same swizzle
  __shared__ u16 Ps[4][32 * 64];     // per-wave P tile [q][m], same swizzle

  const int tid = threadIdx.x;
  const int w = tid >> 6, lane = tid & 63;
  const int l15 = lane & 15, quad = lane >> 4;
  const int bh = blockIdx.x;
  const int b = bh / 12, h = bh - b * 12;
  const int q0 = blockIdx.y * 128 + w * 32;

  short8 qf[2][2];
  {
    const u16* qb = qws + ((size_t)bh * 1024 + q0) * 64;
#pragma unroll
    for (int rt = 0; rt < 2; rt++)
#pragma unroll
      for (int c = 0; c < 2; c++)
        qf[rt][c] = *(const short8*)(qb + (rt * 16 + l15) * 64 + c * 32 + quad * 8);
  }

  const short ONE = (short)0x3F80;  // bf16 1.0
  const short8 onesf = (short8){ONE, ONE, ONE, ONE, ONE, ONE, ONE, ONE};

  float4_t O[2][4];
  float4_t lacc[2];
#pragma unroll
  for (int rt = 0; rt < 2; rt++) {
#pragma unroll
    for (int dt = 0; dt < 4; dt++) O[rt][dt] = (float4_t){0.f, 0.f, 0.f, 0.f};
    lacc[rt] = (float4_t){0.f, 0.f, 0.f, 0.f};
  }

  for (int t = 0; t < 20; t++) {
    const int mb = t * 64;
    __syncthreads();
#pragma unroll
    for (int r = 0; r < 2; r++) {
      const int off = (w * 2 + r) * 1024 + lane * 16;
      const int row = off >> 7;             // 128B per row (64 bf16)
      const int grp = (off & 127) >> 4;     // 0..7
      const int lcol = (grp ^ (row & 7)) * 8;
      const u16* g = (mb < 1024)
          ? kws + ((size_t)bh * 1024 + mb + row) * 64 + lcol
          : bk + ((size_t)h * 256 + (mb - 1024) + row) * 64 + lcol;
      gload16(g, (char*)Ks + off);
      const u16* g2 = (mb < 1024)
          ? vtws + ((size_t)bh * 64 + row) * 1024 + mb + lcol
          : bvt + ((size_t)h * 64 + row) * 256 + (mb - 1024) + lcol;
      gload16(g2, (char*)Vts + off);
    }
    __syncthreads();

    short8 kf[4][2];
#pragma unroll
    for (int ct = 0; ct < 4; ct++)
#pragma unroll
      for (int c = 0; c < 2; c++) {
        const int row = ct * 16 + l15;
        kf[ct][c] = *(const short8*)(Ks + row * 64 + ((c * 4 + quad) ^ (row & 7)) * 8);
      }

    float4_t S[2][4];
#pragma unroll
    for (int rt = 0; rt < 2; rt++)
#pragma unroll
      for (int ct = 0; ct < 4; ct++) {
        float4_t z = (float4_t){0.f, 0.f, 0.f, 0.f};
        z = __builtin_amdgcn_mfma_f32_16x16x32_bf16(qf[rt][0], kf[ct][0], z, 0, 0, 0);
        S[rt][ct] = __builtin_amdgcn_mfma_f32_16x16x32_bf16(qf[rt][1], kf[ct][1], z, 0, 0, 0);
      }

    // exp2 (scores bounded, no overflow) + truncating bf16 pack -> LDS
#pragma unroll
    for (int rt = 0; rt < 2; rt++) {
#pragma unroll
      for (int ct = 0; ct < 4; ct++) {
        const int colg = ct * 2 + (l15 >> 3);
#pragma unroll
        for (int r = 0; r < 4; r++) {
          const float p = __builtin_amdgcn_exp2f(S[rt][ct][r]);
          const int q = rt * 16 + quad * 4 + r;
          Ps[w][q * 64 + (colg ^ (q & 7)) * 8 + (l15 & 7)] = f2bf_trunc(p);
        }
      }
    }

    short8 vf[4][2];
#pragma unroll
    for (int dt = 0; dt < 4; dt++)
#pragma unroll
      for (int c = 0; c < 2; c++) {
        const int row = dt * 16 + l15;
        vf[dt][c] = *(const short8*)(Vts + row * 64 + ((c * 4 + quad) ^ (row & 7)) * 8);
      }
#pragma unroll
    for (int rt = 0; rt < 2; rt++)
#pragma unroll
      for (int c = 0; c < 2; c++) {
        const int qrow = rt * 16 + l15;
        const short8 pf = *(const short8*)(&Ps[w][qrow * 64 + (((c * 4 + quad) ^ (qrow & 7)) * 8)]);
#pragma unroll
        for (int dt = 0; dt < 4; dt++)
          O[rt][dt] = __builtin_amdgcn_mfma_f32_16x16x32_bf16(pf, vf[dt][c], O[rt][dt], 0, 0, 0);
        lacc[rt] = __builtin_amdgcn_mfma_f32_16x16x32_bf16(pf, onesf, lacc[rt], 0, 0, 0);
      }
  }

#pragma unroll
  for (int rt = 0; rt < 2; rt++) {
    float rl[4];
#pragma unroll
    for (int r = 0; r < 4; r++) rl[r] = 1.f / lacc[rt][r];
#pragma unroll
    for (int dt = 0; dt < 4; dt++)
#pragma unroll
      for (int r = 0; r < 4; r++) {
        const float v = O[rt][dt][r] * rl[r];
        const int n = q0 + rt * 16 + quad * 4 + r;
        const int d = dt * 16 + l15;
        const size_t idx = ((size_t)b * 1024 + n) * 768 + h * 64 + d;
        out[idx] = v;
        obf[idx] = f2bf(v);
      }
  }
}

// ---------------- in-place LayerNorm over 768 ----------------
__global__ __launch_bounds__(256) void ln_kernel(float* __restrict__ p,
                                                 const float* __restrict__ nw,
                                                 const float* __restrict__ nb) {
  __shared__ float red[2][4];
  const int row = blockIdx.x, tid = threadIdx.x;
  float* pr = p + (size_t)row * 768;
  const float x0 = pr[tid], x1 = pr[tid + 256], x2 = pr[tid + 512];
  float s = x0 + x1 + x2;
  float sq = x0 * x0 + x1 * x1 + x2 * x2;
#pragma unroll
  for (int m = 1; m < 64; m <<= 1) {
    s += __shfl_xor(s, m, 64);
    sq += __shfl_xor(sq, m, 64);
  }
  const int w = tid >> 6;
  if ((tid & 63) == 0) { red[0][w] = s; red[1][w] = sq; }
  __syncthreads();
  s = red[0][0] + red[0][1] + red[0][2] + red[0][3];
  sq = red[1][0] + red[1][1] + red[1][2] + red[1][3];
  const float mean = s * (1.0f / 768.0f);
  const float var = sq * (1.0f / 768.0f) - mean * mean;
  const float rstd = rsqrtf(var + 1e-5f);
  pr[tid]       = (x0 - mean) * rstd * nw[tid]       + nb[tid];
  pr[tid + 256] = (x1 - mean) * rstd * nw[tid + 256] + nb[tid + 256];
  pr[tid + 512] = (x2 - mean) * rstd * nw[tid + 512] + nb[tid + 512];
}

extern "C" void kernel_launch(void* const* d_in, const int* in_sizes, int n_in,
                              void* d_out, int out_size, void* d_ws, size_t ws_size,
                              hipStream_t stream) {
  (void)in_sizes; (void)n_in; (void)out_size; (void)ws_size;
  const float* x      = (const float*)d_in[0];
  const float* qkv_w  = (const float*)d_in[1];
  const float* qkv_b  = (const float*)d_in[2];
  const float* proj_w = (const float*)d_in[3];
  const float* proj_b = (const float*)d_in[4];
  const float* norm_w = (const float*)d_in[5];
  const float* norm_b = (const float*)d_in[6];
  const float* bank_k = (const float*)d_in[7];
  const float* bank_v = (const float*)d_in[8];

  char* ws = (char*)d_ws;
  u16* xbf   = (u16*)(ws + 0);           // 16384x768 bf16 = 25165824
  u16* obf   = (u16*)(ws + 0);           // aliases xbf (dead after gemm<0>)
  u16* qwbf  = (u16*)(ws + 25165824);    // 2304x768  = 3538944
  u16* pwbf  = (u16*)(ws + 28704768);    // 768x768   = 1179648
  u16* bkbf  = (u16*)(ws + 29884416);    // 12x256x64 = 393216
  u16* bvtbf = (u16*)(ws + 30277632);    // 12x64x256 = 393216
  u16* q_ws  = (u16*)(ws + 30670848);    // 192x1024x64 = 25165824
  u16* k_ws  = (u16*)(ws + 55836672);
  u16* vt_ws = (u16*)(ws + 81002496);    // ends 106168320

  float* out0  = (float*)d_out;
  float* p_out = out0 + 12582912;        // second output region doubles as p scratch

  cvt_kernel<<<12288, 256, 0, stream>>>(x, xbf, 3145728);
  cvt_kernel<<<1728, 256, 0, stream>>>(qkv_w, qwbf, 442368);
  cvt_kernel<<<576, 256, 0, stream>>>(proj_w, pwbf, 147456);
  cvt_bank_kernel<<<768, 256, 0, stream>>>(bank_k, bank_v, bkbf, bvtbf);

  gemm128<0><<<dim3(18, 128), 256, 0, stream>>>(xbf, qwbf, qkv_b, q_ws, k_ws, vt_ws, nullptr);
  fa_kernel<<<dim3(192, 8), 256, 0, stream>>>(q_ws, k_ws, vt_ws, bkbf, bvtbf, out0, obf);
  gemm128<1><<<dim3(6, 128), 256, 0, stream>>>(obf, pwbf, proj_b, nullptr, nullptr, nullptr, p_out);
  ln_kernel<<<16384, 256, 0, stream>>>(p_out, norm_w, norm_b);
}

// Round 6
// 431.481 us; speedup vs baseline: 1.4010x; 1.0207x over previous
//
#include <hip/hip_runtime.h>

typedef __attribute__((ext_vector_type(8))) short short8;
typedef __attribute__((ext_vector_type(4))) float float4_t;
typedef unsigned short u16;

#define K_DIM 768

__device__ __forceinline__ u16 f2bf(float f) {
  union { float f; unsigned u; } v; v.f = f;
  unsigned r = v.u + 0x7FFFu + ((v.u >> 16) & 1u);
  return (u16)(r >> 16);
}

__device__ __forceinline__ u16 f2bf_trunc(float f) {
  union { float f; unsigned u; } v; v.f = f;
  return (u16)(v.u >> 16);
}

__device__ __forceinline__ void gload16(const void* g, void* l) {
  __builtin_amdgcn_global_load_lds(
      (__attribute__((address_space(1))) void*)g,
      (__attribute__((address_space(3))) void*)l, 16, 0, 0);
}

// ---------------- fused fp32->bf16 converts + bank re-layout ----------------
// blocks [0,14592): vectorized convert of x / qkv_w / proj_w (block-aligned ranges)
// blocks [14592,15360): bank_k -> bk[h][m][d], bank_v -> bvt[h][d][m]
__global__ __launch_bounds__(256) void cvt_all_kernel(
    const float* __restrict__ x, const float* __restrict__ qw,
    const float* __restrict__ pw, const float* __restrict__ bkf,
    const float* __restrict__ bvf,
    u16* __restrict__ xbf, u16* __restrict__ qwbf, u16* __restrict__ pwbf,
    u16* __restrict__ bk, u16* __restrict__ bvt) {
  const int blk = blockIdx.x;
  if (blk < 14592) {
    int i = blk * 256 + threadIdx.x;
    const float* src; u16* dst;
    if (i < 3145728)      { src = x;  dst = xbf; }
    else if (i < 3588096) { src = qw; dst = qwbf; i -= 3145728; }
    else                  { src = pw; dst = pwbf; i -= 3588096; }
    float4 v = ((const float4*)src)[i];
    union { u16 h[4]; unsigned long long ll; } o;
    o.h[0] = f2bf(v.x); o.h[1] = f2bf(v.y); o.h[2] = f2bf(v.z); o.h[3] = f2bf(v.w);
    ((unsigned long long*)dst)[i] = o.ll;
  } else {
    int idx = (blk - 14592) * 256 + threadIdx.x;  // < 196608
    int m = idx / 768;
    int c = idx - m * 768;
    int h = c >> 6, d = c & 63;
    bk[(h * 256 + m) * 64 + d] = f2bf(bkf[idx]);
    bvt[(h * 64 + d) * 256 + m] = f2bf(bvf[idx]);
  }
}

// ---------------- 128x128x32 bf16 GEMM, C = A * B^T  ----------------
template <int MODE>
__global__ __launch_bounds__(256) void gemm128(
    const u16* __restrict__ A, const u16* __restrict__ Bw,
    const float* __restrict__ bias,
    u16* __restrict__ q_ws, u16* __restrict__ k_ws, u16* __restrict__ vt_ws,
    float* __restrict__ p_out) {
  __shared__ u16 As[128 * 32];
  __shared__ u16 Bs[128 * 32];
  const int tid = threadIdx.x;
  const int w = tid >> 6, lane = tid & 63;
  const int l15 = lane & 15, quad = lane >> 4;
  const int wm = w >> 1, wn = w & 1;
  const int bm = blockIdx.y, bn = blockIdx.x;

  float4_t acc[4][4];
#pragma unroll
  for (int i = 0; i < 4; i++)
#pragma unroll
    for (int j = 0; j < 4; j++) acc[i][j] = (float4_t){0.f, 0.f, 0.f, 0.f};

  for (int kt = 0; kt < K_DIM; kt += 32) {
    __syncthreads();
#pragma unroll
    for (int r = 0; r < 2; r++) {
      const int off = (w * 2 + r) * 1024 + lane * 16;  // byte offset in 8KB tile
      const int row = off >> 6;                        // 64B per row (32 bf16)
      const int grp = (off & 63) >> 4;                 // phys 16B group 0..3
      const int lcol = (grp ^ (row & 3)) * 8;          // XOR-swizzled logical col
      gload16(A + (size_t)(bm * 128 + row) * K_DIM + kt + lcol, (char*)As + off);
      gload16(Bw + (size_t)(bn * 128 + row) * K_DIM + kt + lcol, (char*)Bs + off);
    }
    __syncthreads();
    short8 af[4], bfr[4];
#pragma unroll
    for (int mt = 0; mt < 4; mt++) {
      const int row = wm * 64 + mt * 16 + l15;
      af[mt] = *(const short8*)(As + row * 32 + (quad ^ (row & 3)) * 8);
    }
#pragma unroll
    for (int nt = 0; nt < 4; nt++) {
      const int row = wn * 64 + nt * 16 + l15;
      bfr[nt] = *(const short8*)(Bs + row * 32 + (quad ^ (row & 3)) * 8);
    }
#pragma unroll
    for (int mt = 0; mt < 4; mt++)
#pragma unroll
      for (int nt = 0; nt < 4; nt++)
        acc[mt][nt] = __builtin_amdgcn_mfma_f32_16x16x32_bf16(af[mt], bfr[nt], acc[mt][nt], 0, 0, 0);
  }

  const float QS = 0.18033688011112042f;  // (1/8) * log2(e)
#pragma unroll
  for (int mt = 0; mt < 4; mt++) {
#pragma unroll
    for (int nt = 0; nt < 4; nt++) {
      const int row0 = bm * 128 + wm * 64 + mt * 16 + quad * 4;
      const int f = bn * 128 + wn * 64 + nt * 16 + l15;
      const float bv = bias[f];
      if (MODE == 0) {
        const int which = f / 768;
        const int rem = f - which * 768;
        const int h = rem >> 6, d = rem & 63;
#pragma unroll
        for (int r2 = 0; r2 < 4; r2++) {
          float v = acc[mt][nt][r2] + bv;
          const int i = row0 + r2;
          const int bb = i >> 10, n = i & 1023;
          const size_t bhh = (size_t)(bb * 12 + h);
          if (which == 0)      q_ws[(bhh * 1024 + n) * 64 + d] = f2bf(v * QS);
          else if (which == 1) k_ws[(bhh * 1024 + n) * 64 + d] = f2bf(v);
          else                 vt_ws[(bhh * 64 + d) * 1024 + n] = f2bf(v);
        }
      } else {
#pragma unroll
        for (int r2 = 0; r2 < 4; r2++) {
          const int i = row0 + r2;
          p_out[(size_t)i * 768 + f] = acc[mt][nt][r2] + bv;
        }
      }
    }
  }
}

// ---------------- flash attention (LDS-staged K/V, Ps aliased onto K/V) ----
// grid (192 bh, 8 qblocks): the 8 q-blocks sharing one bh's K/V have block
// ids ≡ bh (mod 8) -> same XCD -> staging loads hit that XCD's L2.
// LDS = 16 KB total: Ks[8K]+Vts[8K]; after kf/vf are register-resident
// (3rd barrier), the same region holds the 4 per-wave P tiles (4 KB each).
__global__ __launch_bounds__(256) void fa_kernel(
    const u16* __restrict__ qws, const u16* __restrict__ kws,
    const u16* __restrict__ vtws, const u16* __restrict__ bk,
    const u16* __restrict__ bvt,
    float* __restrict__ out, u16* __restrict__ obf) {
  __shared__ u16 smem[8192];         // 16 KB, triple-purpose
  u16* Ks  = smem;                   // [m][d] 64x64, rows XOR-swizzled (16B grp)
  u16* Vts = smem + 4096;            // [d][m] 64x64, same swizzle

  const int tid = threadIdx.x;
  const int w = tid >> 6, lane = tid & 63;
  const int l15 = lane & 15, quad = lane >> 4;
  u16* Psw = smem + w * 2048;        // per-wave P tile [q][m] 32x64, swizzled
  const int bh = blockIdx.x;
  const int b = bh / 12, h = bh - b * 12;
  const int q0 = blockIdx.y * 128 + w * 32;

  short8 qf[2][2];
  {
    const u16* qb = qws + ((size_t)bh * 1024 + q0) * 64;
#pragma unroll
    for (int rt = 0; rt < 2; rt++)
#pragma unroll
      for (int c = 0; c < 2; c++)
        qf[rt][c] = *(const short8*)(qb + (rt * 16 + l15) * 64 + c * 32 + quad * 8);
  }

  const short ONE = (short)0x3F80;  // bf16 1.0
  const short8 onesf = (short8){ONE, ONE, ONE, ONE, ONE, ONE, ONE, ONE};

  float4_t O[2][4];
  float4_t lacc[2];
#pragma unroll
  for (int rt = 0; rt < 2; rt++) {
#pragma unroll
    for (int dt = 0; dt < 4; dt++) O[rt][dt] = (float4_t){0.f, 0.f, 0.f, 0.f};
    lacc[rt] = (float4_t){0.f, 0.f, 0.f, 0.f};
  }

  for (int t = 0; t < 20; t++) {
    const int mb = t * 64;
    __syncthreads();                  // B1: all P reads done before restage
#pragma unroll
    for (int r = 0; r < 2; r++) {
      const int off = (w * 2 + r) * 1024 + lane * 16;
      const int row = off >> 7;             // 128B per row (64 bf16)
      const int grp = (off & 127) >> 4;     // 0..7
      const int lcol = (grp ^ (row & 7)) * 8;
      const u16* g = (mb < 1024)
          ? kws + ((size_t)bh * 1024 + mb + row) * 64 + lcol
          : bk + ((size_t)h * 256 + (mb - 1024) + row) * 64 + lcol;
      gload16(g, (char*)Ks + off);
      const u16* g2 = (mb < 1024)
          ? vtws + ((size_t)bh * 64 + row) * 1024 + mb + lcol
          : bvt + ((size_t)h * 64 + row) * 256 + (mb - 1024) + lcol;
      gload16(g2, (char*)Vts + off);
    }
    __syncthreads();                  // B2: staging visible

    short8 kf[4][2];
#pragma unroll
    for (int ct = 0; ct < 4; ct++)
#pragma unroll
      for (int c = 0; c < 2; c++) {
        const int row = ct * 16 + l15;
        kf[ct][c] = *(const short8*)(Ks + row * 64 + ((c * 4 + quad) ^ (row & 7)) * 8);
      }

    float4_t S[2][4];
#pragma unroll
    for (int rt = 0; rt < 2; rt++)
#pragma unroll
      for (int ct = 0; ct < 4; ct++) {
        float4_t z = (float4_t){0.f, 0.f, 0.f, 0.f};
        z = __builtin_amdgcn_mfma_f32_16x16x32_bf16(qf[rt][0], kf[ct][0], z, 0, 0, 0);
        S[rt][ct] = __builtin_amdgcn_mfma_f32_16x16x32_bf16(qf[rt][1], kf[ct][1], z, 0, 0, 0);
      }

    // V fragments into registers BEFORE P overwrites the K/V region
    short8 vf[4][2];
#pragma unroll
    for (int dt = 0; dt < 4; dt++)
#pragma unroll
      for (int c = 0; c < 2; c++) {
        const int row = dt * 16 + l15;
        vf[dt][c] = *(const short8*)(Vts + row * 64 + ((c * 4 + quad) ^ (row & 7)) * 8);
      }

    __syncthreads();                  // B3: all waves done reading Ks/Vts

    // exp2 (scores bounded, no overflow) + truncating bf16 pack -> aliased LDS
#pragma unroll
    for (int rt = 0; rt < 2; rt++) {
#pragma unroll
      for (int ct = 0; ct < 4; ct++) {
        const int colg = ct * 2 + (l15 >> 3);
#pragma unroll
        for (int r = 0; r < 4; r++) {
          const float p = __builtin_amdgcn_exp2f(S[rt][ct][r]);
          const int q = rt * 16 + quad * 4 + r;
          Psw[q * 64 + (colg ^ (q & 7)) * 8 + (l15 & 7)] = f2bf_trunc(p);
        }
      }
    }

#pragma unroll
    for (int rt = 0; rt < 2; rt++)
#pragma unroll
      for (int c = 0; c < 2; c++) {
        const int qrow = rt * 16 + l15;
        const short8 pf = *(const short8*)(&Psw[qrow * 64 + (((c * 4 + quad) ^ (qrow & 7)) * 8)]);
#pragma unroll
        for (int dt = 0; dt < 4; dt++)
          O[rt][dt] = __builtin_amdgcn_mfma_f32_16x16x32_bf16(pf, vf[dt][c], O[rt][dt], 0, 0, 0);
        lacc[rt] = __builtin_amdgcn_mfma_f32_16x16x32_bf16(pf, onesf, lacc[rt], 0, 0, 0);
      }
  }

#pragma unroll
  for (int rt = 0; rt < 2; rt++) {
    float rl[4];
#pragma unroll
    for (int r = 0; r < 4; r++) rl[r] = 1.f / lacc[rt][r];
#pragma unroll
    for (int dt = 0; dt < 4; dt++)
#pragma unroll
      for (int r = 0; r < 4; r++) {
        const float v = O[rt][dt][r] * rl[r];
        const int n = q0 + rt * 16 + quad * 4 + r;
        const int d = dt * 16 + l15;
        const size_t idx = ((size_t)b * 1024 + n) * 768 + h * 64 + d;
        out[idx] = v;
        obf[idx] = f2bf(v);
      }
  }
}

// ---------------- in-place LayerNorm over 768 ----------------
__global__ __launch_bounds__(256) void ln_kernel(float* __restrict__ p,
                                                 const float* __restrict__ nw,
                                                 const float* __restrict__ nb) {
  __shared__ float red[2][4];
  const int row = blockIdx.x, tid = threadIdx.x;
  float* pr = p + (size_t)row * 768;
  const float x0 = pr[tid], x1 = pr[tid + 256], x2 = pr[tid + 512];
  float s = x0 + x1 + x2;
  float sq = x0 * x0 + x1 * x1 + x2 * x2;
#pragma unroll
  for (int m = 1; m < 64; m <<= 1) {
    s += __shfl_xor(s, m, 64);
    sq += __shfl_xor(sq, m, 64);
  }
  const int w = tid >> 6;
  if ((tid & 63) == 0) { red[0][w] = s; red[1][w] = sq; }
  __syncthreads();
  s = red[0][0] + red[0][1] + red[0][2] + red[0][3];
  sq = red[1][0] + red[1][1] + red[1][2] + red[1][3];
  const float mean = s * (1.0f / 768.0f);
  const float var = sq * (1.0f / 768.0f) - mean * mean;
  const float rstd = rsqrtf(var + 1e-5f);
  pr[tid]       = (x0 - mean) * rstd * nw[tid]       + nb[tid];
  pr[tid + 256] = (x1 - mean) * rstd * nw[tid + 256] + nb[tid + 256];
  pr[tid + 512] = (x2 - mean) * rstd * nw[tid + 512] + nb[tid + 512];
}

extern "C" void kernel_launch(void* const* d_in, const int* in_sizes, int n_in,
                              void* d_out, int out_size, void* d_ws, size_t ws_size,
                              hipStream_t stream) {
  (void)in_sizes; (void)n_in; (void)out_size; (void)ws_size;
  const float* x      = (const float*)d_in[0];
  const float* qkv_w  = (const float*)d_in[1];
  const float* qkv_b  = (const float*)d_in[2];
  const float* proj_w = (const float*)d_in[3];
  const float* proj_b = (const float*)d_in[4];
  const float* norm_w = (const float*)d_in[5];
  const float* norm_b = (const float*)d_in[6];
  const float* bank_k = (const float*)d_in[7];
  const float* bank_v = (const float*)d_in[8];

  char* ws = (char*)d_ws;
  u16* xbf   = (u16*)(ws + 0);           // 16384x768 bf16 = 25165824
  u16* obf   = (u16*)(ws + 0);           // aliases xbf (dead after gemm<0>)
  u16* qwbf  = (u16*)(ws + 25165824);    // 2304x768  = 3538944
  u16* pwbf  = (u16*)(ws + 28704768);    // 768x768   = 1179648
  u16* bkbf  = (u16*)(ws + 29884416);    // 12x256x64 = 393216
  u16* bvtbf = (u16*)(ws + 30277632);    // 12x64x256 = 393216
  u16* q_ws  = (u16*)(ws + 30670848);    // 192x1024x64 = 25165824
  u16* k_ws  = (u16*)(ws + 55836672);
  u16* vt_ws = (u16*)(ws + 81002496);    // ends 106168320

  float* out0  = (float*)d_out;
  float* p_out = out0 + 12582912;        // second output region doubles as p scratch

  cvt_all_kernel<<<15360, 256, 0, stream>>>(x, qkv_w, proj_w, bank_k, bank_v,
                                            xbf, qwbf, pwbf, bkbf, bvtbf);

  gemm128<0><<<dim3(18, 128), 256, 0, stream>>>(xbf, qwbf, qkv_b, q_ws, k_ws, vt_ws, nullptr);
  fa_kernel<<<dim3(192, 8), 256, 0, stream>>>(q_ws, k_ws, vt_ws, bkbf, bvtbf, out0, obf);
  gemm128<1><<<dim3(6, 128), 256, 0, stream>>>(obf, pwbf, proj_b, nullptr, nullptr, nullptr, p_out);
  ln_kernel<<<16384, 256, 0, stream>>>(p_out, norm_w, norm_b);
}